// Round 14
// baseline (197.399 us; speedup 1.0000x reference)
//
#include <hip/hip_runtime.h>
#include <hip/hip_bf16.h>

static __device__ __forceinline__ float elu_f(float x) {
    return x > 0.f ? x : expm1f(x);
}

static __device__ __forceinline__ ushort f2bf(float x) {
    __hip_bfloat16 h = __float2bfloat16(x);
    ushort u;
    __builtin_memcpy(&u, &h, 2);
    return u;
}

typedef short bf16x8 __attribute__((ext_vector_type(8)));
typedef float f32x4  __attribute__((ext_vector_type(4)));
typedef float floatx2 __attribute__((ext_vector_type(2)));

#if __has_builtin(__builtin_amdgcn_cvt_pk_f32_fp8) && __has_builtin(__builtin_amdgcn_cvt_pk_fp8_f32)
#define FP8_HW 1
#else
#define FP8_HW 0
#endif

// -------- SW e4m3fn codec (fallback only) --------
static __device__ __forceinline__ float fp8_to_f32_sw(uint b) {
    uint s = (b & 0x80u) << 24;
    uint e = (b >> 3) & 0xfu, m = b & 7u;
    float v = (e == 0) ? ((float)m * 0x1p-9f)
                       : __uint_as_float(((e + 120u) << 23) | (m << 20));
    return __uint_as_float(s | __float_as_uint(v));
}

static __device__ __forceinline__ uint f32_to_fp8_sw(float x) {
    float c = fminf(fmaxf(x, -448.f), 448.f);
    uint s = (__float_as_uint(c) >> 24) & 0x80u;
    float a = fabsf(c);
    uint bits;
    if (a < 0x1p-6f) {
        int mi = (int)rintf(a * 0x1p9f);
        bits = (mi >= 8) ? 0x08u : (uint)mi;
    } else {
        uint u = __float_as_uint(a);
        int eb = (int)((u >> 23) & 0xff) - 127;
        float sc = a * exp2f((float)(3 - eb));
        int q = (int)rintf(sc);
        if (q >= 16) { q = 8; eb += 1; }
        bits = (eb > 8) ? 0x7eu : (((uint)(eb + 7) << 3) | (uint)(q - 8));
    }
    return s | bits;
}

static __device__ __forceinline__ uchar f2fp8(float v) {
#if FP8_HW
    return (uchar)((uint)__builtin_amdgcn_cvt_pk_fp8_f32(v, v, 0, false) & 0xffu);
#else
    return (uchar)f32_to_fp8_sw(v);
#endif
}

static __device__ __forceinline__ void fp8x4_unpack(uint w, float* f) {
#if FP8_HW
    floatx2 p0 = __builtin_amdgcn_cvt_pk_f32_fp8((int)w, false);
    floatx2 p1 = __builtin_amdgcn_cvt_pk_f32_fp8((int)w, true);
    f[0] = p0[0]; f[1] = p0[1]; f[2] = p1[0]; f[3] = p1[1];
#else
    f[0] = fp8_to_f32_sw(w & 0xffu);
    f[1] = fp8_to_f32_sw((w >> 8) & 0xffu);
    f[2] = fp8_to_f32_sw((w >> 16) & 0xffu);
    f[3] = fp8_to_f32_sw(w >> 24);
#endif
}

static __device__ __forceinline__ void fp8x16_unpack(uint4 v, float* f) {
    fp8x4_unpack(v.x, f);
    fp8x4_unpack(v.y, f + 4);
    fp8x4_unpack(v.z, f + 8);
    fp8x4_unpack(v.w, f + 12);
}

static __device__ __forceinline__ void bf8_unpack(uint4 v, float* f) {
    f[0] = __uint_as_float(v.x << 16);
    f[1] = __uint_as_float(v.x & 0xffff0000u);
    f[2] = __uint_as_float(v.y << 16);
    f[3] = __uint_as_float(v.y & 0xffff0000u);
    f[4] = __uint_as_float(v.z << 16);
    f[5] = __uint_as_float(v.z & 0xffff0000u);
    f[6] = __uint_as_float(v.w << 16);
    f[7] = __uint_as_float(v.w & 0xffff0000u);
}

static __device__ __forceinline__ uint4 bf8_pack(const float* a) {
    uint4 o;
    o.x = (uint)f2bf(a[0]) | ((uint)f2bf(a[1]) << 16);
    o.y = (uint)f2bf(a[2]) | ((uint)f2bf(a[3]) << 16);
    o.z = (uint)f2bf(a[4]) | ((uint)f2bf(a[5]) << 16);
    o.w = (uint)f2bf(a[6]) | ((uint)f2bf(a[7]) << 16);
    return o;
}

// ================= W prep + bucket count, one dispatch =================
__global__ __launch_bounds__(256) void
k_wprep_count(const float* __restrict__ W1, const float* __restrict__ W2,
              const float* __restrict__ W3, const float* __restrict__ W4,
              ushort* __restrict__ T1, ushort* __restrict__ T2,
              ushort* __restrict__ T3, ushort* __restrict__ T4,
              const int* __restrict__ col, int* __restrict__ bcnt,
              int E, int bspan, int nW) {
    const int b = blockIdx.x;
    if (b < nW) {
        const float* W; ushort* T; int K, base;
        if      (b < 48)  { W = W1; T = T1; K = 128; base = b;       }
        else if (b < 96)  { W = W2; T = T2; K = 128; base = b - 48;  }
        else if (b < 132) { W = W3; T = T3; K = 96;  base = b - 96;  }
        else              { W = W4; T = T4; K = 96;  base = b - 132; }
        const int i = base * 256 + threadIdx.x;
        const int kk = i / 96, c = i - kk * 96;
        T[c * K + kk] = f2bf(W[i]);
    } else {
        __shared__ int h[256];
        const int tid = threadIdx.x;
        h[tid] = 0;
        __syncthreads();
        const int e0 = (b - nW) * 4096;
        #pragma unroll
        for (int j = 0; j < 16; ++j) {
            int e = e0 + j * 256 + tid;
            if (e < E) atomicAdd(&h[col[e] / bspan], 1);
        }
        __syncthreads();
        if (h[tid] > 0) atomicAdd(&bcnt[tid], h[tid]);
    }
}

// ================= bucketed CSR build =================
__global__ __launch_bounds__(256) void
k_bscatter(const int* __restrict__ row, const int* __restrict__ col,
           const float* __restrict__ w, const int* __restrict__ bcnt,
           int* __restrict__ bRes, int2* __restrict__ ebuf, int* __restrict__ edst,
           int E, int bspan) {
    __shared__ int h[256];
    __shared__ int base[256];
    __shared__ int sOff[256];
    __shared__ int wsum[4];
    const int tid = threadIdx.x, lane = tid & 63, wid = tid >> 6;
    h[tid] = 0;
    const int bc = bcnt[tid];
    __syncthreads();
    const int e0 = blockIdx.x * 4096;
    int bk[16], rk[16];
    #pragma unroll
    for (int j = 0; j < 16; ++j) {
        int e = e0 + j * 256 + tid;
        if (e < E) {
            int b = col[e] / bspan;
            bk[j] = b;
            rk[j] = atomicAdd(&h[b], 1);
        }
    }
    {
        int s = bc;
        #pragma unroll
        for (int d = 1; d < 64; d <<= 1) {
            int t = __shfl_up(s, d);
            if (lane >= d) s += t;
        }
        if (lane == 63) wsum[wid] = s;
        __syncthreads();
        int wb = 0;
        #pragma unroll
        for (int k = 0; k < 3; ++k) if (k < wid) wb += wsum[k];
        sOff[tid] = s - bc + wb;
    }
    __syncthreads();
    base[tid] = (h[tid] > 0) ? (sOff[tid] + atomicAdd(&bRes[tid], h[tid])) : 0;
    __syncthreads();
    #pragma unroll
    for (int j = 0; j < 16; ++j) {
        int e = e0 + j * 256 + tid;
        if (e < E) {
            int pos = base[bk[j]] + rk[j];
            ebuf[pos] = make_int2(row[e], __float_as_int(w[e]));
            edst[pos] = col[e];
        }
    }
}

__global__ __launch_bounds__(256) void
k_csrify(const int2* __restrict__ ebuf, const int* __restrict__ edst,
         const int* __restrict__ bcnt, int* __restrict__ off, float* __restrict__ dinv,
         int2* __restrict__ pairs, int N, int E, int bspan) {
    __shared__ int hist[256];
    __shared__ float degs[256];
    __shared__ int curl[256];
    __shared__ int wsum[4];
    __shared__ int sE0;
    const int tid = threadIdx.x, b = blockIdx.x;
    const int lane = tid & 63, wid = tid >> 6;
    const int base = b * bspan;
    const int lnodes = (N - base < bspan) ? (N - base) : bspan;
    if (b == 0 && tid == 0) off[N] = E;
    if (lnodes <= 0) return;
    hist[tid] = 0;
    degs[tid] = 0.f;
    const int bc = bcnt[tid];
    {
        int s = bc;
        #pragma unroll
        for (int d = 1; d < 64; d <<= 1) {
            int t = __shfl_up(s, d);
            if (lane >= d) s += t;
        }
        if (lane == 63) wsum[wid] = s;
        __syncthreads();
        int wb = 0;
        #pragma unroll
        for (int k = 0; k < 3; ++k) if (k < wid) wb += wsum[k];
        if (tid == b) sE0 = s - bc + wb;
    }
    __syncthreads();
    const int e0 = sE0, e1 = sE0 + bcnt[b];
    for (int e = e0 + tid; e < e1; e += 256) {
        int d = edst[e] - base;
        atomicAdd(&hist[d], 1);
        atomicAdd(&degs[d], __int_as_float(ebuf[e].y));
    }
    __syncthreads();
    int v = hist[tid];
    int s = v;
    #pragma unroll
    for (int d = 1; d < 64; d <<= 1) {
        int t = __shfl_up(s, d);
        if (lane >= d) s += t;
    }
    if (lane == 63) wsum[wid] = s;
    __syncthreads();
    int wb = 0;
    #pragma unroll
    for (int k = 0; k < 3; ++k) if (k < wid) wb += wsum[k];
    int excl = s - v + wb;
    if (tid < lnodes) {
        off[base + tid] = e0 + excl;
        dinv[base + tid] = rsqrtf(1.0f + degs[tid]);
    }
    curl[tid] = excl;
    __syncthreads();
    for (int e = e0 + tid; e < e1; e += 256) {
        int d = edst[e] - base;
        int p = atomicAdd(&curl[d], 1);
        pairs[e0 + p] = ebuf[e];
    }
}

// ================= MFMA GEMM body =================
template<int K, int XBF>
__device__ __forceinline__ void gemm_body(
    const void* __restrict__ Xv, const ushort* __restrict__ Wt,
    const float* __restrict__ bias, const float* __restrict__ dscale,
    void* __restrict__ outp, int N, int act, int ofp8, int bid) {
    constexpr int KP = K + 8;
    __shared__ ushort XT[64 * KP];
    __shared__ ushort WT[96 * KP];
    const int tid = threadIdx.x;
    const int n0  = bid * 64;

    #pragma unroll
    for (int i = tid; i < 96 * K / 8; i += 256) {
        const int c = i / (K / 8), q = i - c * (K / 8);
        uint4 v = reinterpret_cast<const uint4*>(Wt)[i];
        *reinterpret_cast<uint4*>(&WT[c * KP + q * 8]) = v;
    }
    if (XBF) {
        const ushort* X = (const ushort*)Xv;
        #pragma unroll
        for (int i = tid; i < 64 * K / 8; i += 256) {
            const int row = i / (K / 8), q = i - row * (K / 8);
            const int n = (n0 + row < N) ? (n0 + row) : (N - 1);
            uint4 v = *reinterpret_cast<const uint4*>(X + (size_t)n * K + q * 8);
            *reinterpret_cast<uint4*>(&XT[row * KP + q * 8]) = v;
        }
    } else {
        const float* X = (const float*)Xv;
        #pragma unroll
        for (int i = tid; i < 64 * K / 4; i += 256) {
            const int row = i / (K / 4), q = i - row * (K / 4);
            const int n = (n0 + row < N) ? (n0 + row) : (N - 1);
            float4 v = *reinterpret_cast<const float4*>(X + (size_t)n * K + q * 4);
            uint lo = (uint)f2bf(v.x) | ((uint)f2bf(v.y) << 16);
            uint hi = (uint)f2bf(v.z) | ((uint)f2bf(v.w) << 16);
            *reinterpret_cast<uint2*>(&XT[row * KP + q * 4]) = make_uint2(lo, hi);
        }
    }
    __syncthreads();

    const int lane = tid & 63;
    const int wv   = tid >> 6;
    const int r16  = lane & 15;
    const int kh   = lane >> 4;

    bf16x8 a[K / 32];
    const ushort* xbase = &XT[(wv * 16 + r16) * KP + kh * 8];
    #pragma unroll
    for (int ks = 0; ks < K / 32; ++ks)
        a[ks] = *reinterpret_cast<const bf16x8*>(xbase + ks * 32);

    f32x4 acc[6];
    #pragma unroll
    for (int ct = 0; ct < 6; ++ct) {
        f32x4 c = {0.f, 0.f, 0.f, 0.f};
        const ushort* wbase = &WT[(ct * 16 + r16) * KP + kh * 8];
        #pragma unroll
        for (int ks = 0; ks < K / 32; ++ks) {
            bf16x8 bfr = *reinterpret_cast<const bf16x8*>(wbase + ks * 32);
            c = __builtin_amdgcn_mfma_f32_16x16x32_bf16(a[ks], bfr, c, 0, 0, 0);
        }
        acc[ct] = c;
    }

    #pragma unroll
    for (int r = 0; r < 4; ++r) {
        const int n = n0 + wv * 16 + kh * 4 + r;
        if (n >= N) continue;
        const float ds = dscale ? dscale[n] : 1.f;
        #pragma unroll
        for (int ct = 0; ct < 6; ++ct) {
            const int col = ct * 16 + r16;
            float v = acc[ct][r] * ds;
            if (bias) v += bias[col];
            if (act) v = elu_f(v);
            if (ofp8) ((uchar*)outp)[(size_t)n * 96 + col] = f2fp8(v);
            else      ((ushort*)outp)[(size_t)n * 96 + col] = f2bf(v);
        }
    }
}

__global__ __launch_bounds__(256) void
k_gemm_fin_dual(const float* __restrict__ X,
                const ushort* __restrict__ Wt1, const float* __restrict__ dscale1,
                void* __restrict__ out1,
                const ushort* __restrict__ Wt2, const float* __restrict__ bias2,
                void* __restrict__ out2, int N, int nHalf) {
    if ((int)blockIdx.x < nHalf)
        gemm_body<128, 0>(X, Wt1, nullptr, dscale1, out1, N, 0, 1, blockIdx.x);
    else
        gemm_body<128, 0>(X, Wt2, bias2, nullptr, out2, N, 1, 0, blockIdx.x - nHalf);
}

// ================= aggregation body (fp8 messages, LDS pairs, depth-3) =================
#define AGG_CAP 2048

__device__ __forceinline__ void agg_body(
    const uchar* __restrict__ tmp, const int* __restrict__ off,
    const int2* __restrict__ pairs, const float* __restrict__ dinv,
    const float* __restrict__ bias, const ushort* __restrict__ addsrc,
    ushort* __restrict__ out, int N, int bid) {
    __shared__ int2 eP[AGG_CAP];
    __shared__ int sFlag;
    const int tid = threadIdx.x;
    const int t0  = bid * 256;
    int n_first = t0 / 6;
    if (n_first >= N) return;
    int n_last = (t0 + 255) / 6;
    if (n_last >= N) n_last = N - 1;
    const int eb0 = off[n_first];
    const int eb1 = off[n_last + 1];
    const int tot = eb1 - eb0;
    if (tot <= AGG_CAP) {
        for (int i = tid; i < tot; i += 256) eP[i] = pairs[eb0 + i];
        if (tid == 0) sFlag = 1;
    } else if (tid == 0) sFlag = 0;
    __syncthreads();
    const bool lds = (sFlag != 0);

    const int n = (t0 + tid) / 6;
    if (n >= N) return;
    const int c = ((t0 + tid) % 6) * 16;
    const uchar* base = tmp + c;

    auto LOADP = [&](int e) -> int2 { return lds ? eP[e - eb0] : pairs[e]; };

    const float di = dinv[n];
    float f[16], acc[16];
    {
        uint4 sv = *reinterpret_cast<const uint4*>(base + (size_t)n * 96);
        fp8x16_unpack(sv, f);
        #pragma unroll
        for (int i = 0; i < 16; ++i) acc[i] = f[i];
    }

    const int e0 = off[n];
    const int e1 = off[n + 1];
    const int m  = e1 - e0;

    int2 pA, pB, pC;
    uint4 hA, hB, hC;
    if (m > 0) { pA = LOADP(e0);     hA = *reinterpret_cast<const uint4*>(base + (size_t)pA.x * 96); }
    if (m > 1) { pB = LOADP(e0 + 1); hB = *reinterpret_cast<const uint4*>(base + (size_t)pB.x * 96); }
    if (m > 2) { pC = LOADP(e0 + 2); hC = *reinterpret_cast<const uint4*>(base + (size_t)pC.x * 96); }

    for (int e = e0 + 3; e < e1; ++e) {
        int2 pD = LOADP(e);
        uint4 hD = *reinterpret_cast<const uint4*>(base + (size_t)pD.x * 96);
        float w = __int_as_float(pA.y);
        fp8x16_unpack(hA, f);
        #pragma unroll
        for (int i = 0; i < 16; ++i) acc[i] = fmaf(w, f[i], acc[i]);
        pA = pB; hA = hB;
        pB = pC; hB = hC;
        pC = pD; hC = hD;
    }
    if (m > 0) {
        float w = __int_as_float(pA.y);
        fp8x16_unpack(hA, f);
        #pragma unroll
        for (int i = 0; i < 16; ++i) acc[i] = fmaf(w, f[i], acc[i]);
    }
    if (m > 1) {
        float w = __int_as_float(pB.y);
        fp8x16_unpack(hB, f);
        #pragma unroll
        for (int i = 0; i < 16; ++i) acc[i] = fmaf(w, f[i], acc[i]);
    }
    if (m > 2) {
        float w = __int_as_float(pC.y);
        fp8x16_unpack(hC, f);
        #pragma unroll
        for (int i = 0; i < 16; ++i) acc[i] = fmaf(w, f[i], acc[i]);
    }

    #pragma unroll
    for (int q = 0; q < 4; ++q) {
        float4 bv = *reinterpret_cast<const float4*>(bias + c + q * 4);
        acc[q * 4 + 0] = elu_f(fmaf(di, acc[q * 4 + 0], bv.x));
        acc[q * 4 + 1] = elu_f(fmaf(di, acc[q * 4 + 1], bv.y));
        acc[q * 4 + 2] = elu_f(fmaf(di, acc[q * 4 + 2], bv.z));
        acc[q * 4 + 3] = elu_f(fmaf(di, acc[q * 4 + 3], bv.w));
    }
    if (addsrc) {
        uint4 r0 = *reinterpret_cast<const uint4*>(addsrc + (size_t)n * 96 + c);
        uint4 r1 = *reinterpret_cast<const uint4*>(addsrc + (size_t)n * 96 + c + 8);
        bf8_unpack(r0, f);
        bf8_unpack(r1, f + 8);
        #pragma unroll
        for (int i = 0; i < 16; ++i) acc[i] += f[i];
    }
    ushort* op = out + (size_t)n * 96 + c;
    *reinterpret_cast<uint4*>(op)     = bf8_pack(acc);
    *reinterpret_cast<uint4*>(op + 8) = bf8_pack(acc + 8);
}

__global__ __launch_bounds__(256) void
k_aggregate(const uchar* __restrict__ tmp, const int* __restrict__ off,
            const int2* __restrict__ pairs, const float* __restrict__ dinv,
            const float* __restrict__ bias, const ushort* __restrict__ addsrc,
            ushort* __restrict__ out, int N) {
    agg_body(tmp, off, pairs, dinv, bias, addsrc, out, N, blockIdx.x);
}

// agg1 (M1 -> Bb) || gemm2 (Cb -> M2): independent stages, one dispatch
__global__ __launch_bounds__(256) void
k_agg1_gemm2(const uchar* __restrict__ M1, const int* __restrict__ off,
             const int2* __restrict__ pairs, const float* __restrict__ dinv,
             const float* __restrict__ bc1, ushort* __restrict__ Bb,
             const ushort* __restrict__ Cb, const ushort* __restrict__ Wt2,
             uchar* __restrict__ M2, int N, int nAgg) {
    if ((int)blockIdx.x < nAgg)
        agg_body(M1, off, pairs, dinv, bc1, nullptr, Bb, N, blockIdx.x);
    else
        gemm_body<96, 1>(Cb, Wt2, nullptr, dinv, M2, N, 0, 1, (int)blockIdx.x - nAgg);
}

// ================= fused agg2 + gemm3: 64 nodes/block, 384 threads =================
// Phase A (agg): 6 thr/node aggregate M2 -> h2 rows, ELU, write bf16 to LDS.
// Phase B (gemm): 6 waves compute h2 @ Wc3 (K=96), scale by dinv, store fp8 M3.
#define FKP 104

__global__ __launch_bounds__(384) void
k_agg2_gemm3(const uchar* __restrict__ M2, const int* __restrict__ off,
             const int2* __restrict__ pairs, const float* __restrict__ dinv,
             const float* __restrict__ bc2, const ushort* __restrict__ Wt3,
             uchar* __restrict__ M3, int N) {
    __shared__ ushort XT[64 * FKP];    // h2 tile, bf16
    __shared__ ushort WT[96 * FKP];    // Wc3^T
    __shared__ int2 eP[AGG_CAP];
    __shared__ int sFlag;
    const int tid = threadIdx.x;
    const int n0  = blockIdx.x * 64;

    // stage Wc3^T (independent of M2)
    for (int i = tid; i < 96 * 96 / 8; i += 384) {
        const int c = i / 12, q = i - c * 12;
        uint4 v = reinterpret_cast<const uint4*>(Wt3)[i];
        *reinterpret_cast<uint4*>(&WT[c * FKP + q * 8]) = v;
    }
    // stage pairs for this block's 64 nodes
    int n_last = (n0 + 63 < N) ? (n0 + 63) : (N - 1);
    const int eb0 = off[n0];
    const int eb1 = off[n_last + 1];
    const int tot = eb1 - eb0;
    if (tot <= AGG_CAP) {
        for (int i = tid; i < tot; i += 384) eP[i] = pairs[eb0 + i];
        if (tid == 0) sFlag = 1;
    } else if (tid == 0) sFlag = 0;
    __syncthreads();
    const bool lds = (sFlag != 0);

    // ---- Phase A: aggregate ----
    const int n = n0 + tid / 6;
    const int c = (tid % 6) * 16;
    float acc[16];
    if (n < N) {
        const uchar* base = M2 + c;
        auto LOADP = [&](int e) -> int2 { return lds ? eP[e - eb0] : pairs[e]; };
        float f[16];
        {
            uint4 sv = *reinterpret_cast<const uint4*>(base + (size_t)n * 96);
            fp8x16_unpack(sv, f);
            #pragma unroll
            for (int i = 0; i < 16; ++i) acc[i] = f[i];
        }
        const int e0 = off[n];
        const int e1 = off[n + 1];
        const int m  = e1 - e0;
        int2 pA, pB, pC;
        uint4 hA, hB, hC;
        if (m > 0) { pA = LOADP(e0);     hA = *reinterpret_cast<const uint4*>(base + (size_t)pA.x * 96); }
        if (m > 1) { pB = LOADP(e0 + 1); hB = *reinterpret_cast<const uint4*>(base + (size_t)pB.x * 96); }
        if (m > 2) { pC = LOADP(e0 + 2); hC = *reinterpret_cast<const uint4*>(base + (size_t)pC.x * 96); }
        for (int e = e0 + 3; e < e1; ++e) {
            int2 pD = LOADP(e);
            uint4 hD = *reinterpret_cast<const uint4*>(base + (size_t)pD.x * 96);
            float w = __int_as_float(pA.y);
            fp8x16_unpack(hA, f);
            #pragma unroll
            for (int i = 0; i < 16; ++i) acc[i] = fmaf(w, f[i], acc[i]);
            pA = pB; hA = hB;
            pB = pC; hB = hC;
            pC = pD; hC = hD;
        }
        if (m > 0) {
            float w = __int_as_float(pA.y);
            fp8x16_unpack(hA, f);
            #pragma unroll
            for (int i = 0; i < 16; ++i) acc[i] = fmaf(w, f[i], acc[i]);
        }
        if (m > 1) {
            float w = __int_as_float(pB.y);
            fp8x16_unpack(hB, f);
            #pragma unroll
            for (int i = 0; i < 16; ++i) acc[i] = fmaf(w, f[i], acc[i]);
        }
        if (m > 2) {
            float w = __int_as_float(pC.y);
            fp8x16_unpack(hC, f);
            #pragma unroll
            for (int i = 0; i < 16; ++i) acc[i] = fmaf(w, f[i], acc[i]);
        }
        const float di = dinv[n];
        #pragma unroll
        for (int q = 0; q < 4; ++q) {
            float4 bv = *reinterpret_cast<const float4*>(bc2 + c + q * 4);
            acc[q * 4 + 0] = elu_f(fmaf(di, acc[q * 4 + 0], bv.x));
            acc[q * 4 + 1] = elu_f(fmaf(di, acc[q * 4 + 1], bv.y));
            acc[q * 4 + 2] = elu_f(fmaf(di, acc[q * 4 + 2], bv.z));
            acc[q * 4 + 3] = elu_f(fmaf(di, acc[q * 4 + 3], bv.w));
        }
    } else {
        #pragma unroll
        for (int i = 0; i < 16; ++i) acc[i] = 0.f;
    }
    // write h2 row chunk to XT (bf16) — same rounding as the old global round-trip
    {
        ushort* xp = &XT[(tid / 6) * FKP + c];
        *reinterpret_cast<uint4*>(xp)     = bf8_pack(acc);
        *reinterpret_cast<uint4*>(xp + 8) = bf8_pack(acc + 8);
    }
    __syncthreads();

    // ---- Phase B: GEMM h2 @ Wc3, 6 waves x (1 col-tile, 4 row-tiles) ----
    const int lane = tid & 63;
    const int ct   = tid >> 6;        // 0..5 col tile
    const int r16  = lane & 15;
    const int kh   = lane >> 4;

    bf16x8 b[3];
    const ushort* wbase = &WT[(ct * 16 + r16) * FKP + kh * 8];
    #pragma unroll
    for (int ks = 0; ks < 3; ++ks)
        b[ks] = *reinterpret_cast<const bf16x8*>(wbase + ks * 32);

    #pragma unroll
    for (int rt = 0; rt < 4; ++rt) {
        f32x4 d = {0.f, 0.f, 0.f, 0.f};
        const ushort* xb = &XT[(rt * 16 + r16) * FKP + kh * 8];
        #pragma unroll
        for (int ks = 0; ks < 3; ++ks) {
            bf16x8 a = *reinterpret_cast<const bf16x8*>(xb + ks * 32);
            d = __builtin_amdgcn_mfma_f32_16x16x32_bf16(a, b[ks], d, 0, 0, 0);
        }
        const int col = ct * 16 + r16;
        #pragma unroll
        for (int r = 0; r < 4; ++r) {
            const int nrow = n0 + rt * 16 + kh * 4 + r;
            if (nrow < N)
                M3[(size_t)nrow * 96 + col] = f2fp8(d[r] * dinv[nrow]);
        }
    }
}

// ================= final: logits + log_softmax (lane = node, bf16 LDS) =================
__global__ __launch_bounds__(128) void
k_lin2_lsm(const ushort* __restrict__ h, const float* __restrict__ W2,
           const float* __restrict__ b2, float* __restrict__ out, int N) {
    __shared__ ushort hsT[96][128];   // 24 KiB
    const int tid = threadIdx.x;
    const int n0 = blockIdx.x * 128;
    const int nn = (N - n0 < 128) ? (N - n0) : 128;

    if (tid < nn) {
        const ushort* hr = h + (size_t)(n0 + tid) * 96;
        #pragma unroll
        for (int q = 0; q < 12; ++q) {
            uint4 v = *reinterpret_cast<const uint4*>(hr + q * 8);
            hsT[q * 8 + 0][tid] = (ushort)(v.x & 0xffffu);
            hsT[q * 8 + 1][tid] = (ushort)(v.x >> 16);
            hsT[q * 8 + 2][tid] = (ushort)(v.y & 0xffffu);
            hsT[q * 8 + 3][tid] = (ushort)(v.y >> 16);
            hsT[q * 8 + 4][tid] = (ushort)(v.z & 0xffffu);
            hsT[q * 8 + 5][tid] = (ushort)(v.z >> 16);
            hsT[q * 8 + 6][tid] = (ushort)(v.w & 0xffffu);
            hsT[q * 8 + 7][tid] = (ushort)(v.w >> 16);
        }
    }
    __syncthreads();

    float acc[40];
    #pragma unroll
    for (int c = 0; c < 40; ++c) acc[c] = b2[c];
    for (int k = 0; k < 96; ++k) {
        const float hv = __uint_as_float((uint)hsT[k][tid] << 16);
        const float* wr = W2 + k * 40;
        #pragma unroll
        for (int c = 0; c < 40; ++c) acc[c] = fmaf(hv, wr[c], acc[c]);
    }

    float m = acc[0];
    #pragma unroll
    for (int c = 1; c < 40; ++c) m = fmaxf(m, acc[c]);
    float s = 0.f;
    #pragma unroll
    for (int c = 0; c < 40; ++c) s += expf(acc[c] - m);
    const float lse = m + logf(s);

    if (tid < nn) {
        float* op = out + (size_t)(n0 + tid) * 40;
        #pragma unroll
        for (int q = 0; q < 10; ++q) {
            float4 v = make_float4(acc[q * 4 + 0] - lse, acc[q * 4 + 1] - lse,
                                   acc[q * 4 + 2] - lse, acc[q * 4 + 3] - lse);
            *reinterpret_cast<float4*>(op + q * 4) = v;
        }
    }
}

// ================= launch =================

extern "C" void kernel_launch(void* const* d_in, const int* in_sizes, int n_in,
                              void* d_out, int out_size, void* d_ws, size_t ws_size,
                              hipStream_t stream) {
    const float* x   = (const float*)d_in[0];
    const int*   ei  = (const int*)d_in[1];
    const float* ew  = (const float*)d_in[2];
    const float* Wc1 = (const float*)d_in[3];
    const float* bc1 = (const float*)d_in[4];
    const float* Wc2 = (const float*)d_in[5];
    const float* bc2 = (const float*)d_in[6];
    const float* Wc3 = (const float*)d_in[7];
    const float* bc3 = (const float*)d_in[8];
    const float* Wl1 = (const float*)d_in[9];
    const float* bl1 = (const float*)d_in[10];
    const float* Wl2 = (const float*)d_in[11];
    const float* bl2 = (const float*)d_in[12];

    const int FIN = 128, HID = 96;
    const int N = in_sizes[0] / FIN;
    const int E = in_sizes[2];
    const int* row = ei;
    const int* col = ei + E;
    const int bspan = (N + 255) / 256;

    char* ws = (char*)d_ws;
    size_t o = 0;
    auto alloc = [&](size_t bytes) -> void* {
        void* p = ws + o;
        o += (bytes + 255) & ~(size_t)255;
        return p;
    };
    float*  dinv   = (float*)alloc((size_t)N * 4);
    int*    off    = (int*)  alloc((size_t)(N + 1) * 4);
    int*    bmem   = (int*)  alloc(512 * 4);
    int*    bcnt   = bmem;
    int*    bRes   = bmem + 256;
    int2*   pairs  = (int2*) alloc((size_t)E * 8);
    uchar*  M1     = (uchar*)alloc((size_t)N * HID);
    uchar*  M2     = (uchar*)alloc((size_t)N * HID);
    uchar*  M3     = (uchar*)alloc((size_t)N * HID);
    ushort* Bb     = (ushort*)alloc((size_t)N * HID * 2);
    ushort* Cb     = (ushort*)alloc((size_t)N * HID * 2);
    ushort* Wt_c1  = (ushort*)alloc(96 * 128 * 2);
    ushort* Wt_l1  = (ushort*)alloc(96 * 128 * 2);
    ushort* Wt_c2  = (ushort*)alloc(96 * 96 * 2);
    ushort* Wt_c3  = (ushort*)alloc(96 * 96 * 2);
    int2*   ebuf   = (int2*) alloc((size_t)E * 8);
    int*    edst   = (int*)  alloc((size_t)E * 4);

    const int gBkt  = (E + 4095) / 4096;
    const int nGemm = (N + 63) / 64;
    const int nAgg  = (N * 6 + 255) / 256;

    hipMemsetAsync(bmem, 0, 512 * 4, stream);
    k_wprep_count<<<168 + gBkt, 256, 0, stream>>>(Wc1, Wl1, Wc2, Wc3,
                                                  Wt_c1, Wt_l1, Wt_c2, Wt_c3,
                                                  col, bcnt, E, bspan, 168);

    k_bscatter<<<gBkt, 256, 0, stream>>>(row, col, ew, bcnt, bRes, ebuf, edst, E, bspan);
    k_csrify<<<256, 256, 0, stream>>>(ebuf, edst, bcnt, off, dinv, pairs, N, E, bspan);

    // conv1 GEMM (fp8 messages, dinv-scaled) + lin1 GEMM (bf16 h1)
    k_gemm_fin_dual<<<2 * nGemm, 256, 0, stream>>>(x, Wt_c1, dinv, M1,
                                                   Wt_l1, bl1, Cb, N, nGemm);

    // agg1 (M1 -> Bb) || gemm2 (Cb -> M2)
    k_agg1_gemm2<<<nAgg + nGemm, 256, 0, stream>>>(M1, off, pairs, dinv, bc1, Bb,
                                                   Cb, Wt_c2, M2, N, nAgg);

    // fused agg2 + gemm3 (M2 -> h2 in LDS -> M3)
    k_agg2_gemm3<<<nGemm, 384, 0, stream>>>(M2, off, pairs, dinv, bc2, Wt_c3, M3, N);

    // agg3 (+residual Bb) -> Cb final
    k_aggregate<<<nAgg, 256, 0, stream>>>(M3, off, pairs, dinv, bc3, Bb, Cb, N);

    // lin2 + log_softmax
    k_lin2_lsm<<<(N + 127) / 128, 128, 0, stream>>>(Cb, Wl2, bl2, (float*)d_out, N);
}

// Round 15
// 187.764 us; speedup vs baseline: 1.0513x; 1.0513x over previous
//
#include <hip/hip_runtime.h>
#include <hip/hip_bf16.h>

static __device__ __forceinline__ float elu_f(float x) {
    return x > 0.f ? x : expm1f(x);
}

static __device__ __forceinline__ ushort f2bf(float x) {
    __hip_bfloat16 h = __float2bfloat16(x);
    ushort u;
    __builtin_memcpy(&u, &h, 2);
    return u;
}

typedef short bf16x8 __attribute__((ext_vector_type(8)));
typedef float f32x4  __attribute__((ext_vector_type(4)));
typedef float floatx2 __attribute__((ext_vector_type(2)));

#if __has_builtin(__builtin_amdgcn_cvt_pk_f32_fp8) && __has_builtin(__builtin_amdgcn_cvt_pk_fp8_f32)
#define FP8_HW 1
#else
#define FP8_HW 0
#endif

// -------- SW e4m3fn codec (fallback only) --------
static __device__ __forceinline__ float fp8_to_f32_sw(uint b) {
    uint s = (b & 0x80u) << 24;
    uint e = (b >> 3) & 0xfu, m = b & 7u;
    float v = (e == 0) ? ((float)m * 0x1p-9f)
                       : __uint_as_float(((e + 120u) << 23) | (m << 20));
    return __uint_as_float(s | __float_as_uint(v));
}

static __device__ __forceinline__ uint f32_to_fp8_sw(float x) {
    float c = fminf(fmaxf(x, -448.f), 448.f);
    uint s = (__float_as_uint(c) >> 24) & 0x80u;
    float a = fabsf(c);
    uint bits;
    if (a < 0x1p-6f) {
        int mi = (int)rintf(a * 0x1p9f);
        bits = (mi >= 8) ? 0x08u : (uint)mi;
    } else {
        uint u = __float_as_uint(a);
        int eb = (int)((u >> 23) & 0xff) - 127;
        float sc = a * exp2f((float)(3 - eb));
        int q = (int)rintf(sc);
        if (q >= 16) { q = 8; eb += 1; }
        bits = (eb > 8) ? 0x7eu : (((uint)(eb + 7) << 3) | (uint)(q - 8));
    }
    return s | bits;
}

static __device__ __forceinline__ uchar f2fp8(float v) {
#if FP8_HW
    return (uchar)((uint)__builtin_amdgcn_cvt_pk_fp8_f32(v, v, 0, false) & 0xffu);
#else
    return (uchar)f32_to_fp8_sw(v);
#endif
}

static __device__ __forceinline__ void fp8x4_unpack(uint w, float* f) {
#if FP8_HW
    floatx2 p0 = __builtin_amdgcn_cvt_pk_f32_fp8((int)w, false);
    floatx2 p1 = __builtin_amdgcn_cvt_pk_f32_fp8((int)w, true);
    f[0] = p0[0]; f[1] = p0[1]; f[2] = p1[0]; f[3] = p1[1];
#else
    f[0] = fp8_to_f32_sw(w & 0xffu);
    f[1] = fp8_to_f32_sw((w >> 8) & 0xffu);
    f[2] = fp8_to_f32_sw((w >> 16) & 0xffu);
    f[3] = fp8_to_f32_sw(w >> 24);
#endif
}

static __device__ __forceinline__ void fp8x16_unpack(uint4 v, float* f) {
    fp8x4_unpack(v.x, f);
    fp8x4_unpack(v.y, f + 4);
    fp8x4_unpack(v.z, f + 8);
    fp8x4_unpack(v.w, f + 12);
}

static __device__ __forceinline__ void bf8_unpack(uint4 v, float* f) {
    f[0] = __uint_as_float(v.x << 16);
    f[1] = __uint_as_float(v.x & 0xffff0000u);
    f[2] = __uint_as_float(v.y << 16);
    f[3] = __uint_as_float(v.y & 0xffff0000u);
    f[4] = __uint_as_float(v.z << 16);
    f[5] = __uint_as_float(v.z & 0xffff0000u);
    f[6] = __uint_as_float(v.w << 16);
    f[7] = __uint_as_float(v.w & 0xffff0000u);
}

static __device__ __forceinline__ uint4 bf8_pack(const float* a) {
    uint4 o;
    o.x = (uint)f2bf(a[0]) | ((uint)f2bf(a[1]) << 16);
    o.y = (uint)f2bf(a[2]) | ((uint)f2bf(a[3]) << 16);
    o.z = (uint)f2bf(a[4]) | ((uint)f2bf(a[5]) << 16);
    o.w = (uint)f2bf(a[6]) | ((uint)f2bf(a[7]) << 16);
    return o;
}

// ================= W prep + bucket count, one dispatch =================
__global__ __launch_bounds__(256) void
k_wprep_count(const float* __restrict__ W1, const float* __restrict__ W2,
              const float* __restrict__ W3, const float* __restrict__ W4,
              ushort* __restrict__ T1, ushort* __restrict__ T2,
              ushort* __restrict__ T3, ushort* __restrict__ T4,
              const int* __restrict__ col, int* __restrict__ bcnt,
              int E, int bspan, int nW) {
    const int b = blockIdx.x;
    if (b < nW) {
        const float* W; ushort* T; int K, base;
        if      (b < 48)  { W = W1; T = T1; K = 128; base = b;       }
        else if (b < 96)  { W = W2; T = T2; K = 128; base = b - 48;  }
        else if (b < 132) { W = W3; T = T3; K = 96;  base = b - 96;  }
        else              { W = W4; T = T4; K = 96;  base = b - 132; }
        const int i = base * 256 + threadIdx.x;
        const int kk = i / 96, c = i - kk * 96;
        T[c * K + kk] = f2bf(W[i]);
    } else {
        __shared__ int h[256];
        const int tid = threadIdx.x;
        h[tid] = 0;
        __syncthreads();
        const int e0 = (b - nW) * 4096;
        #pragma unroll
        for (int j = 0; j < 16; ++j) {
            int e = e0 + j * 256 + tid;
            if (e < E) atomicAdd(&h[col[e] / bspan], 1);
        }
        __syncthreads();
        if (h[tid] > 0) atomicAdd(&bcnt[tid], h[tid]);
    }
}

// ================= bucketed CSR build =================
__global__ __launch_bounds__(256) void
k_bscatter(const int* __restrict__ row, const int* __restrict__ col,
           const float* __restrict__ w, const int* __restrict__ bcnt,
           int* __restrict__ bRes, int2* __restrict__ ebuf, int* __restrict__ edst,
           int E, int bspan) {
    __shared__ int h[256];
    __shared__ int base[256];
    __shared__ int sOff[256];
    __shared__ int wsum[4];
    const int tid = threadIdx.x, lane = tid & 63, wid = tid >> 6;
    h[tid] = 0;
    const int bc = bcnt[tid];
    __syncthreads();
    const int e0 = blockIdx.x * 4096;
    int bk[16], rk[16];
    #pragma unroll
    for (int j = 0; j < 16; ++j) {
        int e = e0 + j * 256 + tid;
        if (e < E) {
            int b = col[e] / bspan;
            bk[j] = b;
            rk[j] = atomicAdd(&h[b], 1);
        }
    }
    {
        int s = bc;
        #pragma unroll
        for (int d = 1; d < 64; d <<= 1) {
            int t = __shfl_up(s, d);
            if (lane >= d) s += t;
        }
        if (lane == 63) wsum[wid] = s;
        __syncthreads();
        int wb = 0;
        #pragma unroll
        for (int k = 0; k < 3; ++k) if (k < wid) wb += wsum[k];
        sOff[tid] = s - bc + wb;
    }
    __syncthreads();
    base[tid] = (h[tid] > 0) ? (sOff[tid] + atomicAdd(&bRes[tid], h[tid])) : 0;
    __syncthreads();
    #pragma unroll
    for (int j = 0; j < 16; ++j) {
        int e = e0 + j * 256 + tid;
        if (e < E) {
            int pos = base[bk[j]] + rk[j];
            ebuf[pos] = make_int2(row[e], __float_as_int(w[e]));
            edst[pos] = col[e];
        }
    }
}

__global__ __launch_bounds__(256) void
k_csrify(const int2* __restrict__ ebuf, const int* __restrict__ edst,
         const int* __restrict__ bcnt, int* __restrict__ off, float* __restrict__ dinv,
         int2* __restrict__ pairs, int N, int E, int bspan) {
    __shared__ int hist[256];
    __shared__ float degs[256];
    __shared__ int curl[256];
    __shared__ int wsum[4];
    __shared__ int sE0;
    const int tid = threadIdx.x, b = blockIdx.x;
    const int lane = tid & 63, wid = tid >> 6;
    const int base = b * bspan;
    const int lnodes = (N - base < bspan) ? (N - base) : bspan;
    if (b == 0 && tid == 0) off[N] = E;
    if (lnodes <= 0) return;
    hist[tid] = 0;
    degs[tid] = 0.f;
    const int bc = bcnt[tid];
    {
        int s = bc;
        #pragma unroll
        for (int d = 1; d < 64; d <<= 1) {
            int t = __shfl_up(s, d);
            if (lane >= d) s += t;
        }
        if (lane == 63) wsum[wid] = s;
        __syncthreads();
        int wb = 0;
        #pragma unroll
        for (int k = 0; k < 3; ++k) if (k < wid) wb += wsum[k];
        if (tid == b) sE0 = s - bc + wb;
    }
    __syncthreads();
    const int e0 = sE0, e1 = sE0 + bcnt[b];
    for (int e = e0 + tid; e < e1; e += 256) {
        int d = edst[e] - base;
        atomicAdd(&hist[d], 1);
        atomicAdd(&degs[d], __int_as_float(ebuf[e].y));
    }
    __syncthreads();
    int v = hist[tid];
    int s = v;
    #pragma unroll
    for (int d = 1; d < 64; d <<= 1) {
        int t = __shfl_up(s, d);
        if (lane >= d) s += t;
    }
    if (lane == 63) wsum[wid] = s;
    __syncthreads();
    int wb = 0;
    #pragma unroll
    for (int k = 0; k < 3; ++k) if (k < wid) wb += wsum[k];
    int excl = s - v + wb;
    if (tid < lnodes) {
        off[base + tid] = e0 + excl;
        dinv[base + tid] = rsqrtf(1.0f + degs[tid]);
    }
    curl[tid] = excl;
    __syncthreads();
    for (int e = e0 + tid; e < e1; e += 256) {
        int d = edst[e] - base;
        int p = atomicAdd(&curl[d], 1);
        pairs[e0 + p] = ebuf[e];
    }
}

// ================= MFMA GEMM body =================
template<int K, int XBF>
__device__ __forceinline__ void gemm_body(
    const void* __restrict__ Xv, const ushort* __restrict__ Wt,
    const float* __restrict__ bias, const float* __restrict__ dscale,
    void* __restrict__ outp, int N, int act, int ofp8, int bid) {
    constexpr int KP = K + 8;
    __shared__ ushort XT[64 * KP];
    __shared__ ushort WT[96 * KP];
    const int tid = threadIdx.x;
    const int n0  = bid * 64;

    #pragma unroll
    for (int i = tid; i < 96 * K / 8; i += 256) {
        const int c = i / (K / 8), q = i - c * (K / 8);
        uint4 v = reinterpret_cast<const uint4*>(Wt)[i];
        *reinterpret_cast<uint4*>(&WT[c * KP + q * 8]) = v;
    }
    if (XBF) {
        const ushort* X = (const ushort*)Xv;
        #pragma unroll
        for (int i = tid; i < 64 * K / 8; i += 256) {
            const int row = i / (K / 8), q = i - row * (K / 8);
            const int n = (n0 + row < N) ? (n0 + row) : (N - 1);
            uint4 v = *reinterpret_cast<const uint4*>(X + (size_t)n * K + q * 8);
            *reinterpret_cast<uint4*>(&XT[row * KP + q * 8]) = v;
        }
    } else {
        const float* X = (const float*)Xv;
        #pragma unroll
        for (int i = tid; i < 64 * K / 4; i += 256) {
            const int row = i / (K / 4), q = i - row * (K / 4);
            const int n = (n0 + row < N) ? (n0 + row) : (N - 1);
            float4 v = *reinterpret_cast<const float4*>(X + (size_t)n * K + q * 4);
            uint lo = (uint)f2bf(v.x) | ((uint)f2bf(v.y) << 16);
            uint hi = (uint)f2bf(v.z) | ((uint)f2bf(v.w) << 16);
            *reinterpret_cast<uint2*>(&XT[row * KP + q * 4]) = make_uint2(lo, hi);
        }
    }
    __syncthreads();

    const int lane = tid & 63;
    const int wv   = tid >> 6;
    const int r16  = lane & 15;
    const int kh   = lane >> 4;

    bf16x8 a[K / 32];
    const ushort* xbase = &XT[(wv * 16 + r16) * KP + kh * 8];
    #pragma unroll
    for (int ks = 0; ks < K / 32; ++ks)
        a[ks] = *reinterpret_cast<const bf16x8*>(xbase + ks * 32);

    f32x4 acc[6];
    #pragma unroll
    for (int ct = 0; ct < 6; ++ct) {
        f32x4 c = {0.f, 0.f, 0.f, 0.f};
        const ushort* wbase = &WT[(ct * 16 + r16) * KP + kh * 8];
        #pragma unroll
        for (int ks = 0; ks < K / 32; ++ks) {
            bf16x8 bfr = *reinterpret_cast<const bf16x8*>(wbase + ks * 32);
            c = __builtin_amdgcn_mfma_f32_16x16x32_bf16(a[ks], bfr, c, 0, 0, 0);
        }
        acc[ct] = c;
    }

    #pragma unroll
    for (int r = 0; r < 4; ++r) {
        const int n = n0 + wv * 16 + kh * 4 + r;
        if (n >= N) continue;
        const float ds = dscale ? dscale[n] : 1.f;
        #pragma unroll
        for (int ct = 0; ct < 6; ++ct) {
            const int col = ct * 16 + r16;
            float v = acc[ct][r] * ds;
            if (bias) v += bias[col];
            if (act) v = elu_f(v);
            if (ofp8) ((uchar*)outp)[(size_t)n * 96 + col] = f2fp8(v);
            else      ((ushort*)outp)[(size_t)n * 96 + col] = f2bf(v);
        }
    }
}

__global__ __launch_bounds__(256) void
k_gemm_mfma96(const ushort* __restrict__ X, const ushort* __restrict__ Wt,
              const float* __restrict__ dscale, void* __restrict__ outp, int N) {
    gemm_body<96, 1>(X, Wt, nullptr, dscale, outp, N, 0, 1, blockIdx.x);
}

__global__ __launch_bounds__(256) void
k_gemm_fin_dual(const float* __restrict__ X,
                const ushort* __restrict__ Wt1, const float* __restrict__ dscale1,
                void* __restrict__ out1,
                const ushort* __restrict__ Wt2, const float* __restrict__ bias2,
                void* __restrict__ out2, int N, int nHalf) {
    if ((int)blockIdx.x < nHalf)
        gemm_body<128, 0>(X, Wt1, nullptr, dscale1, out1, N, 0, 1, blockIdx.x);
    else
        gemm_body<128, 0>(X, Wt2, bias2, nullptr, out2, N, 1, 0, blockIdx.x - nHalf);
}

// ================= aggregation body (fp8 messages, LDS pairs, depth-3) =================
#define AGG_CAP 2048

__device__ __forceinline__ void agg_body(
    const uchar* __restrict__ tmp, const int* __restrict__ off,
    const int2* __restrict__ pairs, const float* __restrict__ dinv,
    const float* __restrict__ bias, const ushort* __restrict__ addsrc,
    ushort* __restrict__ out, int N, int bid) {
    __shared__ int2 eP[AGG_CAP];
    __shared__ int sFlag;
    const int tid = threadIdx.x;
    const int t0  = bid * 256;
    int n_first = t0 / 6;
    if (n_first >= N) return;
    int n_last = (t0 + 255) / 6;
    if (n_last >= N) n_last = N - 1;
    const int eb0 = off[n_first];
    const int eb1 = off[n_last + 1];
    const int tot = eb1 - eb0;
    if (tot <= AGG_CAP) {
        for (int i = tid; i < tot; i += 256) eP[i] = pairs[eb0 + i];
        if (tid == 0) sFlag = 1;
    } else if (tid == 0) sFlag = 0;
    __syncthreads();
    const bool lds = (sFlag != 0);

    const int n = (t0 + tid) / 6;
    if (n >= N) return;
    const int c = ((t0 + tid) % 6) * 16;
    const uchar* base = tmp + c;

    auto LOADP = [&](int e) -> int2 { return lds ? eP[e - eb0] : pairs[e]; };

    const float di = dinv[n];
    float f[16], acc[16];
    {
        uint4 sv = *reinterpret_cast<const uint4*>(base + (size_t)n * 96);
        fp8x16_unpack(sv, f);
        #pragma unroll
        for (int i = 0; i < 16; ++i) acc[i] = f[i];
    }

    const int e0 = off[n];
    const int e1 = off[n + 1];
    const int m  = e1 - e0;

    int2 pA, pB, pC;
    uint4 hA, hB, hC;
    if (m > 0) { pA = LOADP(e0);     hA = *reinterpret_cast<const uint4*>(base + (size_t)pA.x * 96); }
    if (m > 1) { pB = LOADP(e0 + 1); hB = *reinterpret_cast<const uint4*>(base + (size_t)pB.x * 96); }
    if (m > 2) { pC = LOADP(e0 + 2); hC = *reinterpret_cast<const uint4*>(base + (size_t)pC.x * 96); }

    for (int e = e0 + 3; e < e1; ++e) {
        int2 pD = LOADP(e);
        uint4 hD = *reinterpret_cast<const uint4*>(base + (size_t)pD.x * 96);
        float w = __int_as_float(pA.y);
        fp8x16_unpack(hA, f);
        #pragma unroll
        for (int i = 0; i < 16; ++i) acc[i] = fmaf(w, f[i], acc[i]);
        pA = pB; hA = hB;
        pB = pC; hB = hC;
        pC = pD; hC = hD;
    }
    if (m > 0) {
        float w = __int_as_float(pA.y);
        fp8x16_unpack(hA, f);
        #pragma unroll
        for (int i = 0; i < 16; ++i) acc[i] = fmaf(w, f[i], acc[i]);
    }
    if (m > 1) {
        float w = __int_as_float(pB.y);
        fp8x16_unpack(hB, f);
        #pragma unroll
        for (int i = 0; i < 16; ++i) acc[i] = fmaf(w, f[i], acc[i]);
    }
    if (m > 2) {
        float w = __int_as_float(pC.y);
        fp8x16_unpack(hC, f);
        #pragma unroll
        for (int i = 0; i < 16; ++i) acc[i] = fmaf(w, f[i], acc[i]);
    }

    #pragma unroll
    for (int q = 0; q < 4; ++q) {
        float4 bv = *reinterpret_cast<const float4*>(bias + c + q * 4);
        acc[q * 4 + 0] = elu_f(fmaf(di, acc[q * 4 + 0], bv.x));
        acc[q * 4 + 1] = elu_f(fmaf(di, acc[q * 4 + 1], bv.y));
        acc[q * 4 + 2] = elu_f(fmaf(di, acc[q * 4 + 2], bv.z));
        acc[q * 4 + 3] = elu_f(fmaf(di, acc[q * 4 + 3], bv.w));
    }
    if (addsrc) {
        uint4 r0 = *reinterpret_cast<const uint4*>(addsrc + (size_t)n * 96 + c);
        uint4 r1 = *reinterpret_cast<const uint4*>(addsrc + (size_t)n * 96 + c + 8);
        bf8_unpack(r0, f);
        bf8_unpack(r1, f + 8);
        #pragma unroll
        for (int i = 0; i < 16; ++i) acc[i] += f[i];
    }
    ushort* op = out + (size_t)n * 96 + c;
    *reinterpret_cast<uint4*>(op)     = bf8_pack(acc);
    *reinterpret_cast<uint4*>(op + 8) = bf8_pack(acc + 8);
}

__global__ __launch_bounds__(256) void
k_aggregate(const uchar* __restrict__ tmp, const int* __restrict__ off,
            const int2* __restrict__ pairs, const float* __restrict__ dinv,
            const float* __restrict__ bias, const ushort* __restrict__ addsrc,
            ushort* __restrict__ out, int N) {
    agg_body(tmp, off, pairs, dinv, bias, addsrc, out, N, blockIdx.x);
}

// agg1 (M1 -> Bb) || gemm2 (Cb -> M2): independent stages, one dispatch
__global__ __launch_bounds__(256) void
k_agg1_gemm2(const uchar* __restrict__ M1, const int* __restrict__ off,
             const int2* __restrict__ pairs, const float* __restrict__ dinv,
             const float* __restrict__ bc1, ushort* __restrict__ Bb,
             const ushort* __restrict__ Cb, const ushort* __restrict__ Wt2,
             uchar* __restrict__ M2, int N, int nAgg) {
    if ((int)blockIdx.x < nAgg)
        agg_body(M1, off, pairs, dinv, bc1, nullptr, Bb, N, blockIdx.x);
    else
        gemm_body<96, 1>(Cb, Wt2, nullptr, dinv, M2, N, 0, 1, (int)blockIdx.x - nAgg);
}

// ================= final: logits + log_softmax (lane = node, bf16 LDS) =================
__global__ __launch_bounds__(128) void
k_lin2_lsm(const ushort* __restrict__ h, const float* __restrict__ W2,
           const float* __restrict__ b2, float* __restrict__ out, int N) {
    __shared__ ushort hsT[96][128];   // 24 KiB
    const int tid = threadIdx.x;
    const int n0 = blockIdx.x * 128;
    const int nn = (N - n0 < 128) ? (N - n0) : 128;

    if (tid < nn) {
        const ushort* hr = h + (size_t)(n0 + tid) * 96;
        #pragma unroll
        for (int q = 0; q < 12; ++q) {
            uint4 v = *reinterpret_cast<const uint4*>(hr + q * 8);
            hsT[q * 8 + 0][tid] = (ushort)(v.x & 0xffffu);
            hsT[q * 8 + 1][tid] = (ushort)(v.x >> 16);
            hsT[q * 8 + 2][tid] = (ushort)(v.y & 0xffffu);
            hsT[q * 8 + 3][tid] = (ushort)(v.y >> 16);
            hsT[q * 8 + 4][tid] = (ushort)(v.z & 0xffffu);
            hsT[q * 8 + 5][tid] = (ushort)(v.z >> 16);
            hsT[q * 8 + 6][tid] = (ushort)(v.w & 0xffffu);
            hsT[q * 8 + 7][tid] = (ushort)(v.w >> 16);
        }
    }
    __syncthreads();

    float acc[40];
    #pragma unroll
    for (int c = 0; c < 40; ++c) acc[c] = b2[c];
    for (int k = 0; k < 96; ++k) {
        const float hv = __uint_as_float((uint)hsT[k][tid] << 16);
        const float* wr = W2 + k * 40;
        #pragma unroll
        for (int c = 0; c < 40; ++c) acc[c] = fmaf(hv, wr[c], acc[c]);
    }

    float m = acc[0];
    #pragma unroll
    for (int c = 1; c < 40; ++c) m = fmaxf(m, acc[c]);
    float s = 0.f;
    #pragma unroll
    for (int c = 0; c < 40; ++c) s += expf(acc[c] - m);
    const float lse = m + logf(s);

    if (tid < nn) {
        float* op = out + (size_t)(n0 + tid) * 40;
        #pragma unroll
        for (int q = 0; q < 10; ++q) {
            float4 v = make_float4(acc[q * 4 + 0] - lse, acc[q * 4 + 1] - lse,
                                   acc[q * 4 + 2] - lse, acc[q * 4 + 3] - lse);
            *reinterpret_cast<float4*>(op + q * 4) = v;
        }
    }
}

// ================= launch =================

extern "C" void kernel_launch(void* const* d_in, const int* in_sizes, int n_in,
                              void* d_out, int out_size, void* d_ws, size_t ws_size,
                              hipStream_t stream) {
    const float* x   = (const float*)d_in[0];
    const int*   ei  = (const int*)d_in[1];
    const float* ew  = (const float*)d_in[2];
    const float* Wc1 = (const float*)d_in[3];
    const float* bc1 = (const float*)d_in[4];
    const float* Wc2 = (const float*)d_in[5];
    const float* bc2 = (const float*)d_in[6];
    const float* Wc3 = (const float*)d_in[7];
    const float* bc3 = (const float*)d_in[8];
    const float* Wl1 = (const float*)d_in[9];
    const float* bl1 = (const float*)d_in[10];
    const float* Wl2 = (const float*)d_in[11];
    const float* bl2 = (const float*)d_in[12];

    const int FIN = 128, HID = 96;
    const int N = in_sizes[0] / FIN;
    const int E = in_sizes[2];
    const int* row = ei;
    const int* col = ei + E;
    const int bspan = (N + 255) / 256;

    char* ws = (char*)d_ws;
    size_t o = 0;
    auto alloc = [&](size_t bytes) -> void* {
        void* p = ws + o;
        o += (bytes + 255) & ~(size_t)255;
        return p;
    };
    float*  dinv   = (float*)alloc((size_t)N * 4);
    int*    off    = (int*)  alloc((size_t)(N + 1) * 4);
    int*    bmem   = (int*)  alloc(512 * 4);
    int*    bcnt   = bmem;
    int*    bRes   = bmem + 256;
    int2*   pairs  = (int2*) alloc((size_t)E * 8);
    uchar*  M1     = (uchar*)alloc((size_t)N * HID);
    uchar*  M2     = (uchar*)alloc((size_t)N * HID);
    uchar*  M3     = (uchar*)alloc((size_t)N * HID);
    ushort* Bb     = (ushort*)alloc((size_t)N * HID * 2);
    ushort* Cb     = (ushort*)alloc((size_t)N * HID * 2);
    ushort* Wt_c1  = (ushort*)alloc(96 * 128 * 2);
    ushort* Wt_l1  = (ushort*)alloc(96 * 128 * 2);
    ushort* Wt_c2  = (ushort*)alloc(96 * 96 * 2);
    ushort* Wt_c3  = (ushort*)alloc(96 * 96 * 2);
    int2*   ebuf   = (int2*) alloc((size_t)E * 8);
    int*    edst   = (int*)  alloc((size_t)E * 4);

    const int gBkt  = (E + 4095) / 4096;
    const int nGemm = (N + 63) / 64;
    const int nAgg  = (N * 6 + 255) / 256;

    hipMemsetAsync(bmem, 0, 512 * 4, stream);
    k_wprep_count<<<168 + gBkt, 256, 0, stream>>>(Wc1, Wl1, Wc2, Wc3,
                                                  Wt_c1, Wt_l1, Wt_c2, Wt_c3,
                                                  col, bcnt, E, bspan, 168);

    k_bscatter<<<gBkt, 256, 0, stream>>>(row, col, ew, bcnt, bRes, ebuf, edst, E, bspan);
    k_csrify<<<256, 256, 0, stream>>>(ebuf, edst, bcnt, off, dinv, pairs, N, E, bspan);

    // conv1 GEMM (fp8 messages, dinv-scaled) + lin1 GEMM (bf16 h1)
    k_gemm_fin_dual<<<2 * nGemm, 256, 0, stream>>>(x, Wt_c1, dinv, M1,
                                                   Wt_l1, bl1, Cb, N, nGemm);

    // agg1 (M1 -> Bb) || gemm2 (Cb -> M2)
    k_agg1_gemm2<<<nAgg + nGemm, 256, 0, stream>>>(M1, off, pairs, dinv, bc1, Bb,
                                                   Cb, Wt_c2, M2, N, nAgg);

    // agg2 (M2 -> Cb)
    k_aggregate<<<nAgg, 256, 0, stream>>>(M2, off, pairs, dinv, bc2, nullptr, Cb, N);

    // gemm3 (Cb -> M3)
    k_gemm_mfma96<<<nGemm, 256, 0, stream>>>(Cb, Wt_c3, dinv, M3, N);

    // agg3 (M3 + Bb -> Cb)
    k_aggregate<<<nAgg, 256, 0, stream>>>(M3, off, pairs, dinv, bc3, Bb, Cb, N);

    // lin2 + log_softmax
    k_lin2_lsm<<<(N + 127) / 128, 128, 0, stream>>>(Cb, Wl2, bl2, (float*)d_out, N);
}

// Round 16
// 186.311 us; speedup vs baseline: 1.0595x; 1.0078x over previous
//
#include <hip/hip_runtime.h>
#include <hip/hip_bf16.h>

static __device__ __forceinline__ float elu_f(float x) {
    return x > 0.f ? x : expm1f(x);
}

static __device__ __forceinline__ ushort f2bf(float x) {
    __hip_bfloat16 h = __float2bfloat16(x);
    ushort u;
    __builtin_memcpy(&u, &h, 2);
    return u;
}

typedef short bf16x8 __attribute__((ext_vector_type(8)));
typedef float f32x4  __attribute__((ext_vector_type(4)));
typedef float floatx2 __attribute__((ext_vector_type(2)));

#if __has_builtin(__builtin_amdgcn_cvt_pk_f32_fp8) && __has_builtin(__builtin_amdgcn_cvt_pk_fp8_f32)
#define FP8_HW 1
#else
#define FP8_HW 0
#endif

// -------- SW e4m3fn codec (fallback only) --------
static __device__ __forceinline__ float fp8_to_f32_sw(uint b) {
    uint s = (b & 0x80u) << 24;
    uint e = (b >> 3) & 0xfu, m = b & 7u;
    float v = (e == 0) ? ((float)m * 0x1p-9f)
                       : __uint_as_float(((e + 120u) << 23) | (m << 20));
    return __uint_as_float(s | __float_as_uint(v));
}

static __device__ __forceinline__ uint f32_to_fp8_sw(float x) {
    float c = fminf(fmaxf(x, -448.f), 448.f);
    uint s = (__float_as_uint(c) >> 24) & 0x80u;
    float a = fabsf(c);
    uint bits;
    if (a < 0x1p-6f) {
        int mi = (int)rintf(a * 0x1p9f);
        bits = (mi >= 8) ? 0x08u : (uint)mi;
    } else {
        uint u = __float_as_uint(a);
        int eb = (int)((u >> 23) & 0xff) - 127;
        float sc = a * exp2f((float)(3 - eb));
        int q = (int)rintf(sc);
        if (q >= 16) { q = 8; eb += 1; }
        bits = (eb > 8) ? 0x7eu : (((uint)(eb + 7) << 3) | (uint)(q - 8));
    }
    return s | bits;
}

static __device__ __forceinline__ uchar f2fp8(float v) {
#if FP8_HW
    return (uchar)((uint)__builtin_amdgcn_cvt_pk_fp8_f32(v, v, 0, false) & 0xffu);
#else
    return (uchar)f32_to_fp8_sw(v);
#endif
}

static __device__ __forceinline__ void fp8x4_unpack(uint w, float* f) {
#if FP8_HW
    floatx2 p0 = __builtin_amdgcn_cvt_pk_f32_fp8((int)w, false);
    floatx2 p1 = __builtin_amdgcn_cvt_pk_f32_fp8((int)w, true);
    f[0] = p0[0]; f[1] = p0[1]; f[2] = p1[0]; f[3] = p1[1];
#else
    f[0] = fp8_to_f32_sw(w & 0xffu);
    f[1] = fp8_to_f32_sw((w >> 8) & 0xffu);
    f[2] = fp8_to_f32_sw((w >> 16) & 0xffu);
    f[3] = fp8_to_f32_sw(w >> 24);
#endif
}

static __device__ __forceinline__ void fp8x16_unpack(uint4 v, float* f) {
    fp8x4_unpack(v.x, f);
    fp8x4_unpack(v.y, f + 4);
    fp8x4_unpack(v.z, f + 8);
    fp8x4_unpack(v.w, f + 12);
}

static __device__ __forceinline__ void bf8_unpack(uint4 v, float* f) {
    f[0] = __uint_as_float(v.x << 16);
    f[1] = __uint_as_float(v.x & 0xffff0000u);
    f[2] = __uint_as_float(v.y << 16);
    f[3] = __uint_as_float(v.y & 0xffff0000u);
    f[4] = __uint_as_float(v.z << 16);
    f[5] = __uint_as_float(v.z & 0xffff0000u);
    f[6] = __uint_as_float(v.w << 16);
    f[7] = __uint_as_float(v.w & 0xffff0000u);
}

static __device__ __forceinline__ uint4 bf8_pack(const float* a) {
    uint4 o;
    o.x = (uint)f2bf(a[0]) | ((uint)f2bf(a[1]) << 16);
    o.y = (uint)f2bf(a[2]) | ((uint)f2bf(a[3]) << 16);
    o.z = (uint)f2bf(a[4]) | ((uint)f2bf(a[5]) << 16);
    o.w = (uint)f2bf(a[6]) | ((uint)f2bf(a[7]) << 16);
    return o;
}

// ================= W prep + bucket count, one dispatch =================
__global__ __launch_bounds__(256) void
k_wprep_count(const float* __restrict__ W1, const float* __restrict__ W2,
              const float* __restrict__ W3, const float* __restrict__ W4,
              ushort* __restrict__ T1, ushort* __restrict__ T2,
              ushort* __restrict__ T3, ushort* __restrict__ T4,
              const int* __restrict__ col, int* __restrict__ bcnt,
              int E, int bspan, int nW) {
    const int b = blockIdx.x;
    if (b < nW) {
        const float* W; ushort* T; int K, base;
        if      (b < 48)  { W = W1; T = T1; K = 128; base = b;       }
        else if (b < 96)  { W = W2; T = T2; K = 128; base = b - 48;  }
        else if (b < 132) { W = W3; T = T3; K = 96;  base = b - 96;  }
        else              { W = W4; T = T4; K = 96;  base = b - 132; }
        const int i = base * 256 + threadIdx.x;
        const int kk = i / 96, c = i - kk * 96;
        T[c * K + kk] = f2bf(W[i]);
    } else {
        __shared__ int h[256];
        const int tid = threadIdx.x;
        h[tid] = 0;
        __syncthreads();
        const int e0 = (b - nW) * 4096;
        #pragma unroll
        for (int j = 0; j < 16; ++j) {
            int e = e0 + j * 256 + tid;
            if (e < E) atomicAdd(&h[col[e] / bspan], 1);
        }
        __syncthreads();
        if (h[tid] > 0) atomicAdd(&bcnt[tid], h[tid]);
    }
}

// ================= bucketed CSR build =================
__global__ __launch_bounds__(256) void
k_bscatter(const int* __restrict__ row, const int* __restrict__ col,
           const float* __restrict__ w, const int* __restrict__ bcnt,
           int* __restrict__ bRes, int2* __restrict__ ebuf, int* __restrict__ edst,
           int E, int bspan) {
    __shared__ int h[256];
    __shared__ int base[256];
    __shared__ int sOff[256];
    __shared__ int wsum[4];
    const int tid = threadIdx.x, lane = tid & 63, wid = tid >> 6;
    h[tid] = 0;
    const int bc = bcnt[tid];
    __syncthreads();
    const int e0 = blockIdx.x * 4096;
    int bk[16], rk[16];
    #pragma unroll
    for (int j = 0; j < 16; ++j) {
        int e = e0 + j * 256 + tid;
        if (e < E) {
            int b = col[e] / bspan;
            bk[j] = b;
            rk[j] = atomicAdd(&h[b], 1);
        }
    }
    {
        int s = bc;
        #pragma unroll
        for (int d = 1; d < 64; d <<= 1) {
            int t = __shfl_up(s, d);
            if (lane >= d) s += t;
        }
        if (lane == 63) wsum[wid] = s;
        __syncthreads();
        int wb = 0;
        #pragma unroll
        for (int k = 0; k < 3; ++k) if (k < wid) wb += wsum[k];
        sOff[tid] = s - bc + wb;
    }
    __syncthreads();
    base[tid] = (h[tid] > 0) ? (sOff[tid] + atomicAdd(&bRes[tid], h[tid])) : 0;
    __syncthreads();
    #pragma unroll
    for (int j = 0; j < 16; ++j) {
        int e = e0 + j * 256 + tid;
        if (e < E) {
            int pos = base[bk[j]] + rk[j];
            ebuf[pos] = make_int2(row[e], __float_as_int(w[e]));
            edst[pos] = col[e];
        }
    }
}

__global__ __launch_bounds__(256) void
k_csrify(const int2* __restrict__ ebuf, const int* __restrict__ edst,
         const int* __restrict__ bcnt, int* __restrict__ off, float* __restrict__ dinv,
         int2* __restrict__ pairs, int N, int E, int bspan) {
    __shared__ int hist[256];
    __shared__ float degs[256];
    __shared__ int curl[256];
    __shared__ int wsum[4];
    __shared__ int sE0;
    const int tid = threadIdx.x, b = blockIdx.x;
    const int lane = tid & 63, wid = tid >> 6;
    const int base = b * bspan;
    const int lnodes = (N - base < bspan) ? (N - base) : bspan;
    if (b == 0 && tid == 0) off[N] = E;
    if (lnodes <= 0) return;
    hist[tid] = 0;
    degs[tid] = 0.f;
    const int bc = bcnt[tid];
    {
        int s = bc;
        #pragma unroll
        for (int d = 1; d < 64; d <<= 1) {
            int t = __shfl_up(s, d);
            if (lane >= d) s += t;
        }
        if (lane == 63) wsum[wid] = s;
        __syncthreads();
        int wb = 0;
        #pragma unroll
        for (int k = 0; k < 3; ++k) if (k < wid) wb += wsum[k];
        if (tid == b) sE0 = s - bc + wb;
    }
    __syncthreads();
    const int e0 = sE0, e1 = sE0 + bcnt[b];
    for (int e = e0 + tid; e < e1; e += 256) {
        int d = edst[e] - base;
        atomicAdd(&hist[d], 1);
        atomicAdd(&degs[d], __int_as_float(ebuf[e].y));
    }
    __syncthreads();
    int v = hist[tid];
    int s = v;
    #pragma unroll
    for (int d = 1; d < 64; d <<= 1) {
        int t = __shfl_up(s, d);
        if (lane >= d) s += t;
    }
    if (lane == 63) wsum[wid] = s;
    __syncthreads();
    int wb = 0;
    #pragma unroll
    for (int k = 0; k < 3; ++k) if (k < wid) wb += wsum[k];
    int excl = s - v + wb;
    if (tid < lnodes) {
        off[base + tid] = e0 + excl;
        dinv[base + tid] = rsqrtf(1.0f + degs[tid]);
    }
    curl[tid] = excl;
    __syncthreads();
    for (int e = e0 + tid; e < e1; e += 256) {
        int d = edst[e] - base;
        int p = atomicAdd(&curl[d], 1);
        pairs[e0 + p] = ebuf[e];
    }
}

// ================= MFMA GEMM body =================
template<int K, int XBF>
__device__ __forceinline__ void gemm_body(
    const void* __restrict__ Xv, const ushort* __restrict__ Wt,
    const float* __restrict__ bias, const float* __restrict__ dscale,
    void* __restrict__ outp, int N, int act, int ofp8, int bid) {
    constexpr int KP = K + 8;
    __shared__ ushort XT[64 * KP];
    __shared__ ushort WT[96 * KP];
    const int tid = threadIdx.x;
    const int n0  = bid * 64;

    #pragma unroll
    for (int i = tid; i < 96 * K / 8; i += 256) {
        const int c = i / (K / 8), q = i - c * (K / 8);
        uint4 v = reinterpret_cast<const uint4*>(Wt)[i];
        *reinterpret_cast<uint4*>(&WT[c * KP + q * 8]) = v;
    }
    if (XBF) {
        const ushort* X = (const ushort*)Xv;
        #pragma unroll
        for (int i = tid; i < 64 * K / 8; i += 256) {
            const int row = i / (K / 8), q = i - row * (K / 8);
            const int n = (n0 + row < N) ? (n0 + row) : (N - 1);
            uint4 v = *reinterpret_cast<const uint4*>(X + (size_t)n * K + q * 8);
            *reinterpret_cast<uint4*>(&XT[row * KP + q * 8]) = v;
        }
    } else {
        const float* X = (const float*)Xv;
        #pragma unroll
        for (int i = tid; i < 64 * K / 4; i += 256) {
            const int row = i / (K / 4), q = i - row * (K / 4);
            const int n = (n0 + row < N) ? (n0 + row) : (N - 1);
            float4 v = *reinterpret_cast<const float4*>(X + (size_t)n * K + q * 4);
            uint lo = (uint)f2bf(v.x) | ((uint)f2bf(v.y) << 16);
            uint hi = (uint)f2bf(v.z) | ((uint)f2bf(v.w) << 16);
            *reinterpret_cast<uint2*>(&XT[row * KP + q * 4]) = make_uint2(lo, hi);
        }
    }
    __syncthreads();

    const int lane = tid & 63;
    const int wv   = tid >> 6;
    const int r16  = lane & 15;
    const int kh   = lane >> 4;

    bf16x8 a[K / 32];
    const ushort* xbase = &XT[(wv * 16 + r16) * KP + kh * 8];
    #pragma unroll
    for (int ks = 0; ks < K / 32; ++ks)
        a[ks] = *reinterpret_cast<const bf16x8*>(xbase + ks * 32);

    f32x4 acc[6];
    #pragma unroll
    for (int ct = 0; ct < 6; ++ct) {
        f32x4 c = {0.f, 0.f, 0.f, 0.f};
        const ushort* wbase = &WT[(ct * 16 + r16) * KP + kh * 8];
        #pragma unroll
        for (int ks = 0; ks < K / 32; ++ks) {
            bf16x8 bfr = *reinterpret_cast<const bf16x8*>(wbase + ks * 32);
            c = __builtin_amdgcn_mfma_f32_16x16x32_bf16(a[ks], bfr, c, 0, 0, 0);
        }
        acc[ct] = c;
    }

    #pragma unroll
    for (int r = 0; r < 4; ++r) {
        const int n = n0 + wv * 16 + kh * 4 + r;
        if (n >= N) continue;
        const float ds = dscale ? dscale[n] : 1.f;
        #pragma unroll
        for (int ct = 0; ct < 6; ++ct) {
            const int col = ct * 16 + r16;
            float v = acc[ct][r] * ds;
            if (bias) v += bias[col];
            if (act) v = elu_f(v);
            if (ofp8) ((uchar*)outp)[(size_t)n * 96 + col] = f2fp8(v);
            else      ((ushort*)outp)[(size_t)n * 96 + col] = f2bf(v);
        }
    }
}

__global__ __launch_bounds__(256) void
k_gemm_mfma96(const ushort* __restrict__ X, const ushort* __restrict__ Wt,
              const float* __restrict__ dscale, void* __restrict__ outp, int N) {
    gemm_body<96, 1>(X, Wt, nullptr, dscale, outp, N, 0, 1, blockIdx.x);
}

__global__ __launch_bounds__(256) void
k_gemm_fin_dual(const float* __restrict__ X,
                const ushort* __restrict__ Wt1, const float* __restrict__ dscale1,
                void* __restrict__ out1,
                const ushort* __restrict__ Wt2, const float* __restrict__ bias2,
                void* __restrict__ out2, int N, int nHalf) {
    if ((int)blockIdx.x < nHalf)
        gemm_body<128, 0>(X, Wt1, nullptr, dscale1, out1, N, 0, 1, blockIdx.x);
    else
        gemm_body<128, 0>(X, Wt2, bias2, nullptr, out2, N, 1, 0, blockIdx.x - nHalf);
}

// ================= aggregation (fp8 messages, LDS pairs, depth-3) =================
#define AGG_CAP 2048

__global__ __launch_bounds__(256) void
k_aggregate(const uchar* __restrict__ tmp, const int* __restrict__ off,
            const int2* __restrict__ pairs, const float* __restrict__ dinv,
            const float* __restrict__ bias, const ushort* __restrict__ addsrc,
            ushort* __restrict__ out, int N) {
    __shared__ int2 eP[AGG_CAP];
    __shared__ int sFlag;
    const int tid = threadIdx.x;
    const int t0  = blockIdx.x * 256;
    int n_first = t0 / 6;
    if (n_first >= N) return;
    int n_last = (t0 + 255) / 6;
    if (n_last >= N) n_last = N - 1;
    const int eb0 = off[n_first];
    const int eb1 = off[n_last + 1];
    const int tot = eb1 - eb0;
    if (tot <= AGG_CAP) {
        for (int i = tid; i < tot; i += 256) eP[i] = pairs[eb0 + i];
        if (tid == 0) sFlag = 1;
    } else if (tid == 0) sFlag = 0;
    __syncthreads();
    const bool lds = (sFlag != 0);

    const int n = (t0 + tid) / 6;
    if (n >= N) return;
    const int c = ((t0 + tid) % 6) * 16;
    const uchar* base = tmp + c;

    auto LOADP = [&](int e) -> int2 { return lds ? eP[e - eb0] : pairs[e]; };

    const float di = dinv[n];
    float f[16], acc[16];
    {
        uint4 sv = *reinterpret_cast<const uint4*>(base + (size_t)n * 96);
        fp8x16_unpack(sv, f);
        #pragma unroll
        for (int i = 0; i < 16; ++i) acc[i] = f[i];
    }

    const int e0 = off[n];
    const int e1 = off[n + 1];
    const int m  = e1 - e0;

    int2 pA, pB, pC;
    uint4 hA, hB, hC;
    if (m > 0) { pA = LOADP(e0);     hA = *reinterpret_cast<const uint4*>(base + (size_t)pA.x * 96); }
    if (m > 1) { pB = LOADP(e0 + 1); hB = *reinterpret_cast<const uint4*>(base + (size_t)pB.x * 96); }
    if (m > 2) { pC = LOADP(e0 + 2); hC = *reinterpret_cast<const uint4*>(base + (size_t)pC.x * 96); }

    for (int e = e0 + 3; e < e1; ++e) {
        int2 pD = LOADP(e);
        uint4 hD = *reinterpret_cast<const uint4*>(base + (size_t)pD.x * 96);
        float w = __int_as_float(pA.y);
        fp8x16_unpack(hA, f);
        #pragma unroll
        for (int i = 0; i < 16; ++i) acc[i] = fmaf(w, f[i], acc[i]);
        pA = pB; hA = hB;
        pB = pC; hB = hC;
        pC = pD; hC = hD;
    }
    if (m > 0) {
        float w = __int_as_float(pA.y);
        fp8x16_unpack(hA, f);
        #pragma unroll
        for (int i = 0; i < 16; ++i) acc[i] = fmaf(w, f[i], acc[i]);
    }
    if (m > 1) {
        float w = __int_as_float(pB.y);
        fp8x16_unpack(hB, f);
        #pragma unroll
        for (int i = 0; i < 16; ++i) acc[i] = fmaf(w, f[i], acc[i]);
    }
    if (m > 2) {
        float w = __int_as_float(pC.y);
        fp8x16_unpack(hC, f);
        #pragma unroll
        for (int i = 0; i < 16; ++i) acc[i] = fmaf(w, f[i], acc[i]);
    }

    #pragma unroll
    for (int q = 0; q < 4; ++q) {
        float4 bv = *reinterpret_cast<const float4*>(bias + c + q * 4);
        acc[q * 4 + 0] = elu_f(fmaf(di, acc[q * 4 + 0], bv.x));
        acc[q * 4 + 1] = elu_f(fmaf(di, acc[q * 4 + 1], bv.y));
        acc[q * 4 + 2] = elu_f(fmaf(di, acc[q * 4 + 2], bv.z));
        acc[q * 4 + 3] = elu_f(fmaf(di, acc[q * 4 + 3], bv.w));
    }
    if (addsrc) {
        uint4 r0 = *reinterpret_cast<const uint4*>(addsrc + (size_t)n * 96 + c);
        uint4 r1 = *reinterpret_cast<const uint4*>(addsrc + (size_t)n * 96 + c + 8);
        bf8_unpack(r0, f);
        bf8_unpack(r1, f + 8);
        #pragma unroll
        for (int i = 0; i < 16; ++i) acc[i] += f[i];
    }
    ushort* op = out + (size_t)n * 96 + c;
    *reinterpret_cast<uint4*>(op)     = bf8_pack(acc);
    *reinterpret_cast<uint4*>(op + 8) = bf8_pack(acc + 8);
}

// ================= final: logits + log_softmax (lane = node, bf16 LDS) =================
__global__ __launch_bounds__(128) void
k_lin2_lsm(const ushort* __restrict__ h, const float* __restrict__ W2,
           const float* __restrict__ b2, float* __restrict__ out, int N) {
    __shared__ ushort hsT[96][128];   // 24 KiB
    const int tid = threadIdx.x;
    const int n0 = blockIdx.x * 128;
    const int nn = (N - n0 < 128) ? (N - n0) : 128;

    if (tid < nn) {
        const ushort* hr = h + (size_t)(n0 + tid) * 96;
        #pragma unroll
        for (int q = 0; q < 12; ++q) {
            uint4 v = *reinterpret_cast<const uint4*>(hr + q * 8);
            hsT[q * 8 + 0][tid] = (ushort)(v.x & 0xffffu);
            hsT[q * 8 + 1][tid] = (ushort)(v.x >> 16);
            hsT[q * 8 + 2][tid] = (ushort)(v.y & 0xffffu);
            hsT[q * 8 + 3][tid] = (ushort)(v.y >> 16);
            hsT[q * 8 + 4][tid] = (ushort)(v.z & 0xffffu);
            hsT[q * 8 + 5][tid] = (ushort)(v.z >> 16);
            hsT[q * 8 + 6][tid] = (ushort)(v.w & 0xffffu);
            hsT[q * 8 + 7][tid] = (ushort)(v.w >> 16);
        }
    }
    __syncthreads();

    float acc[40];
    #pragma unroll
    for (int c = 0; c < 40; ++c) acc[c] = b2[c];
    for (int k = 0; k < 96; ++k) {
        const float hv = __uint_as_float((uint)hsT[k][tid] << 16);
        const float* wr = W2 + k * 40;
        #pragma unroll
        for (int c = 0; c < 40; ++c) acc[c] = fmaf(hv, wr[c], acc[c]);
    }

    float m = acc[0];
    #pragma unroll
    for (int c = 1; c < 40; ++c) m = fmaxf(m, acc[c]);
    float s = 0.f;
    #pragma unroll
    for (int c = 0; c < 40; ++c) s += expf(acc[c] - m);
    const float lse = m + logf(s);

    if (tid < nn) {
        float* op = out + (size_t)(n0 + tid) * 40;
        #pragma unroll
        for (int q = 0; q < 10; ++q) {
            float4 v = make_float4(acc[q * 4 + 0] - lse, acc[q * 4 + 1] - lse,
                                   acc[q * 4 + 2] - lse, acc[q * 4 + 3] - lse);
            *reinterpret_cast<float4*>(op + q * 4) = v;
        }
    }
}

// ================= launch =================

extern "C" void kernel_launch(void* const* d_in, const int* in_sizes, int n_in,
                              void* d_out, int out_size, void* d_ws, size_t ws_size,
                              hipStream_t stream) {
    const float* x   = (const float*)d_in[0];
    const int*   ei  = (const int*)d_in[1];
    const float* ew  = (const float*)d_in[2];
    const float* Wc1 = (const float*)d_in[3];
    const float* bc1 = (const float*)d_in[4];
    const float* Wc2 = (const float*)d_in[5];
    const float* bc2 = (const float*)d_in[6];
    const float* Wc3 = (const float*)d_in[7];
    const float* bc3 = (const float*)d_in[8];
    const float* Wl1 = (const float*)d_in[9];
    const float* bl1 = (const float*)d_in[10];
    const float* Wl2 = (const float*)d_in[11];
    const float* bl2 = (const float*)d_in[12];

    const int FIN = 128, HID = 96;
    const int N = in_sizes[0] / FIN;
    const int E = in_sizes[2];
    const int* row = ei;
    const int* col = ei + E;
    const int bspan = (N + 255) / 256;

    char* ws = (char*)d_ws;
    size_t o = 0;
    auto alloc = [&](size_t bytes) -> void* {
        void* p = ws + o;
        o += (bytes + 255) & ~(size_t)255;
        return p;
    };
    float*  dinv   = (float*)alloc((size_t)N * 4);
    int*    off    = (int*)  alloc((size_t)(N + 1) * 4);
    int*    bmem   = (int*)  alloc(512 * 4);
    int*    bcnt   = bmem;
    int*    bRes   = bmem + 256;
    int2*   pairs  = (int2*) alloc((size_t)E * 8);
    uchar*  M1     = (uchar*)alloc((size_t)N * HID);
    uchar*  M2     = (uchar*)alloc((size_t)N * HID);
    uchar*  M3     = (uchar*)alloc((size_t)N * HID);
    ushort* Bb     = (ushort*)alloc((size_t)N * HID * 2);
    ushort* Cb     = (ushort*)alloc((size_t)N * HID * 2);
    ushort* Wt_c1  = (ushort*)alloc(96 * 128 * 2);
    ushort* Wt_l1  = (ushort*)alloc(96 * 128 * 2);
    ushort* Wt_c2  = (ushort*)alloc(96 * 96 * 2);
    ushort* Wt_c3  = (ushort*)alloc(96 * 96 * 2);
    int2*   ebuf   = (int2*) alloc((size_t)E * 8);
    int*    edst   = (int*)  alloc((size_t)E * 4);

    const int gBkt  = (E + 4095) / 4096;
    const int nGemm = (N + 63) / 64;
    const int nAgg  = (N * 6 + 255) / 256;

    hipMemsetAsync(bmem, 0, 512 * 4, stream);
    k_wprep_count<<<168 + gBkt, 256, 0, stream>>>(Wc1, Wl1, Wc2, Wc3,
                                                  Wt_c1, Wt_l1, Wt_c2, Wt_c3,
                                                  col, bcnt, E, bspan, 168);

    k_bscatter<<<gBkt, 256, 0, stream>>>(row, col, ew, bcnt, bRes, ebuf, edst, E, bspan);
    k_csrify<<<256, 256, 0, stream>>>(ebuf, edst, bcnt, off, dinv, pairs, N, E, bspan);

    // conv1 GEMM (fp8 messages, dinv-scaled) + lin1 GEMM (bf16 h1)
    k_gemm_fin_dual<<<2 * nGemm, 256, 0, stream>>>(x, Wt_c1, dinv, M1,
                                                   Wt_l1, bl1, Cb, N, nGemm);

    // agg1 (M1 -> Bb)
    k_aggregate<<<nAgg, 256, 0, stream>>>(M1, off, pairs, dinv, bc1, nullptr, Bb, N);

    // gemm2 (Cb -> M2)
    k_gemm_mfma96<<<nGemm, 256, 0, stream>>>(Cb, Wt_c2, dinv, M2, N);

    // agg2 (M2 -> Cb)
    k_aggregate<<<nAgg, 256, 0, stream>>>(M2, off, pairs, dinv, bc2, nullptr, Cb, N);

    // gemm3 (Cb -> M3)
    k_gemm_mfma96<<<nGemm, 256, 0, stream>>>(Cb, Wt_c3, dinv, M3, N);

    // agg3 (M3 + Bb -> Cb)
    k_aggregate<<<nAgg, 256, 0, stream>>>(M3, off, pairs, dinv, bc3, Bb, Cb, N);

    // lin2 + log_softmax
    k_lin2_lsm<<<(N + 127) / 128, 128, 0, stream>>>(Cb, Wl2, bl2, (float*)d_out, N);
}